// Round 10
// baseline (225.160 us; speedup 1.0000x reference)
//
#include <hip/hip_runtime.h>
#include <stdint.h>

#define NTOK 16384
#define CDIM 1024
#define DHEAD 256

typedef short s16x8 __attribute__((ext_vector_type(8)));
typedef unsigned short u16x8 __attribute__((ext_vector_type(8)));
typedef _Float16 h16x8 __attribute__((ext_vector_type(8)));
typedef float f32x4 __attribute__((ext_vector_type(4)));
typedef float f32x16 __attribute__((ext_vector_type(16)));

static __device__ __forceinline__ unsigned short f2bf(float f) {
    union { float f; unsigned u; } x; x.f = f;
    unsigned r = (x.u + 0x7fffu + ((x.u >> 16) & 1u)) >> 16;
    return (unsigned short)r;
}
static __device__ __forceinline__ unsigned short f2h(float f) {
    _Float16 h = (_Float16)f;
    return __builtin_bit_cast(unsigned short, h);
}
// Barrier ordering LDS only — global loads stay in flight across it (T4).
static __device__ __forceinline__ void lgkm_barrier() {
    asm volatile("s_waitcnt lgkmcnt(0)" ::: "memory");
    __builtin_amdgcn_s_barrier();
}

// ---------------------------------------------------------------------------
// Kernel 1: partial Gram G[de][e] over an n-chunk + per-channel sums.
// Tile 256(de) x 128(e), eh-split. CO-XCD PLACEMENT: P = t8 + 8*eh + 16*thi
// puts both eh halves AND all 8 (b,h) blocks of a chunk on XCD t8 = chunk%8:
// together they consume FULL 4KB q/k rows; L2 dedups -> HBM fetch = 256 MB.
// 16-row stages with DEPTH-2 register staging (A/B sets, 2 stages in flight
// = 48KB/CU outstanding) + lgkm-only barriers -> continuous HBM demand.
// LDS layout [n-group g][ch ^ g] ushort4: write AND b64 read both <=2-way.
// Regs: acc 64 AGPR + 32 staging + ~40 misc ~ 140 @ launch_bounds(512,2).
// ---------------------------------------------------------------------------
__global__ __launch_bounds__(512, 2)
void k_gram(const float* __restrict__ q, const float* __restrict__ k,
            unsigned short* __restrict__ Gpart, float* __restrict__ Spart, int nchunk)
{
    __shared__ __align__(16) ushort4 lsbuf[2048];          // 16 KB
    ushort4* lq4 = lsbuf;                                  // [4 g][256 ch^g]
    ushort4* lk4 = lsbuf + 1024;                           // [4 g][128 ch^g]

    const int P   = blockIdx.x;
    const int t8  = P & 7;
    const int eh  = (P >> 3) & 1;
    const int thi = P >> 4;
    const int T   = thi * 8 + t8;
    const int bh  = T / nchunk;
    const int chunk = T - bh * nchunk;
    const int b = bh >> 2, h = bh & 3;
    const int rows = NTOK / nchunk;
    const int S    = rows >> 4;          // 16-row stages (even count)
    const int n0c  = chunk * rows;

    const int t = threadIdx.x;
    const int lane = t & 63, w = t >> 6;
    const int l31 = lane & 31, g2 = lane >> 5;
    const int wr = w >> 1, wc = w & 1;

    // staging roles: t<256 load q (64 ch-quads x 4 row-groups);
    //                t in [256,384) load k (32 ch-quads x 4 row-groups)
    const bool qt = t < 256;
    const bool kt = (t >= 256) && (t < 384);
    const int qcq = t >> 2, qrg = t & 3;
    const int kid = t - 256;
    const int kcq = kid >> 2, krg = kid & 3;

    const float* qp = q + ((size_t)(b * NTOK + n0c + qrg * 4)) * CDIM + h * DHEAD + qcq * 4;
    const float* kp = k + ((size_t)(b * NTOK + n0c + krg * 4)) * CDIM + h * DHEAD + eh * 128 + kcq * 4;

    f32x4 qA[4], qB[4];   // depth-2 staging sets (4 rows x 4 ch each)

#define LOADSET(dst, s) do {                                                  \
        if (qt) { _Pragma("unroll") for (int j_ = 0; j_ < 4; ++j_)             \
            dst[j_] = *reinterpret_cast<const f32x4*>(qp + ((size_t)(s) * 16 + j_) * CDIM); } \
        else if (kt) { _Pragma("unroll") for (int j_ = 0; j_ < 4; ++j_)        \
            dst[j_] = *reinterpret_cast<const f32x4*>(kp + ((size_t)(s) * 16 + j_) * CDIM); } \
    } while (0)

    float ssum[4] = {0.f, 0.f, 0.f, 0.f};

#define CONSUME(src) do {                                                     \
        if (qt) {                                                              \
            _Pragma("unroll") for (int c_ = 0; c_ < 4; ++c_) {                 \
                const int ch_ = qcq * 4 + c_;                                  \
                ushort4 p_;                                                    \
                p_.x = f2bf(src[0][c_]); p_.y = f2bf(src[1][c_]);              \
                p_.z = f2bf(src[2][c_]); p_.w = f2bf(src[3][c_]);              \
                ssum[c_] += (src[0][c_] + src[1][c_]) + (src[2][c_] + src[3][c_]); \
                lq4[qrg * 256 + (ch_ ^ qrg)] = p_;                             \
            }                                                                  \
        } else if (kt) {                                                       \
            _Pragma("unroll") for (int c_ = 0; c_ < 4; ++c_) {                 \
                const int ch_ = kcq * 4 + c_;                                  \
                ushort4 p_;                                                    \
                p_.x = f2bf(src[0][c_]); p_.y = f2bf(src[1][c_]);              \
                p_.z = f2bf(src[2][c_]); p_.w = f2bf(src[3][c_]);              \
                ssum[c_] += (src[0][c_] + src[1][c_]) + (src[2][c_] + src[3][c_]); \
                lk4[krg * 128 + (ch_ ^ krg)] = p_;                             \
            }                                                                  \
        }                                                                      \
    } while (0)

    f32x16 acc[2][2];
#pragma unroll
    for (int r = 0; r < 2; ++r)
#pragma unroll
        for (int c = 0; c < 2; ++c)
#pragma unroll
            for (int j = 0; j < 16; ++j) acc[r][c][j] = 0.f;

    const uint2* lqu = reinterpret_cast<const uint2*>(lq4);
    const uint2* lku = reinterpret_cast<const uint2*>(lk4);
    const int gLo = 2 * g2, gHi = 2 * g2 + 1;

#define MFMAPHASE() do {                                                      \
        s16x8 af_[2], bf_[2];                                                 \
        _Pragma("unroll") for (int r_ = 0; r_ < 2; ++r_) {                    \
            const int ch_ = wr * 64 + r_ * 32 + l31;                          \
            const uint2 lo_ = lqu[gLo * 256 + (ch_ ^ gLo)];                   \
            const uint2 hi_ = lqu[gHi * 256 + (ch_ ^ gHi)];                   \
            int4 f_; f_.x = lo_.x; f_.y = lo_.y; f_.z = hi_.x; f_.w = hi_.y;  \
            af_[r_] = __builtin_bit_cast(s16x8, f_);                          \
        }                                                                      \
        _Pragma("unroll") for (int c_ = 0; c_ < 2; ++c_) {                    \
            const int ch_ = wc * 64 + c_ * 32 + l31;                          \
            const uint2 lo_ = lku[gLo * 128 + (ch_ ^ gLo)];                   \
            const uint2 hi_ = lku[gHi * 128 + (ch_ ^ gHi)];                   \
            int4 f_; f_.x = lo_.x; f_.y = lo_.y; f_.z = hi_.x; f_.w = hi_.y;  \
            bf_[c_] = __builtin_bit_cast(s16x8, f_);                          \
        }                                                                      \
        _Pragma("unroll") for (int r_ = 0; r_ < 2; ++r_)                      \
            _Pragma("unroll") for (int c_ = 0; c_ < 2; ++c_)                  \
                acc[r_][c_] = __builtin_amdgcn_mfma_f32_32x32x16_bf16(        \
                    af_[r_], bf_[c_], acc[r_][c_], 0, 0, 0);                  \
    } while (0)

    LOADSET(qA, 0);
    LOADSET(qB, 1);

    for (int s = 0; s < S; s += 2) {
        CONSUME(qA);
        if (s + 2 < S) LOADSET(qA, s + 2);
        lgkm_barrier();
        MFMAPHASE();
        lgkm_barrier();

        CONSUME(qB);
        if (s + 3 < S) LOADSET(qB, s + 3);
        lgkm_barrier();
        MFMAPHASE();
        lgkm_barrier();
    }
#undef LOADSET
#undef CONSUME
#undef MFMAPHASE

    // ---- channel sums: reduce over the 4-row-group lanes (t&3) ----
#pragma unroll
    for (int off = 1; off < 4; off <<= 1)
#pragma unroll
        for (int c = 0; c < 4; ++c) ssum[c] += __shfl_xor(ssum[c], off);
    float* sp = Spart + (size_t)(bh * nchunk + chunk) * 512;
    if (qt && (t & 3) == 0)
        *reinterpret_cast<float4*>(&sp[qcq * 4]) = make_float4(ssum[0], ssum[1], ssum[2], ssum[3]);
    if (kt && (kid & 3) == 0)
        *reinterpret_cast<float4*>(&sp[256 + eh * 128 + kcq * 4]) =
            make_float4(ssum[0], ssum[1], ssum[2], ssum[3]);

    // ---- Gpart (fp16) via LDS transpose: 4 quarters of 64 de x 128 e ----
    unsigned short* ls = reinterpret_cast<unsigned short*>(lsbuf);   // 8192 u16
    unsigned short* gp = Gpart + (size_t)(bh * nchunk + chunk) * 65536;
#pragma unroll
    for (int qtr = 0; qtr < 4; ++qtr) {
        if (wr == qtr) {
#pragma unroll
            for (int r = 0; r < 2; ++r)
#pragma unroll
                for (int c = 0; c < 2; ++c)
#pragma unroll
                    for (int reg = 0; reg < 16; ++reg) {
                        const int de_l = r * 32 + (reg & 3) + 8 * (reg >> 2) + 4 * g2;
                        const int e_l  = wc * 64 + c * 32 + l31;
                        ls[de_l * 128 + e_l] = f2h(acc[r][c][reg]);
                    }
        }
        lgkm_barrier();
#pragma unroll
        for (int i = 0; i < 2; ++i) {
            const int idx = i * 512 + t;           // 0..1023
            const int row = idx >> 4, col = (idx & 15) * 8;
            *reinterpret_cast<u16x8*>(gp + (size_t)(qtr * 64 + row) * 256 + eh * 128 + col) =
                *reinterpret_cast<const u16x8*>(&ls[row * 128 + col]);
        }
        lgkm_barrier();
    }
}

// ---------------------------------------------------------------------------
// Kernel 2: fused chunk-reduce + scores + softmax (both branches) + W/beta.
// W written in k_out's fragment order: Wf[bh][ks=e/32][dd][e%32] bf16.
// ---------------------------------------------------------------------------
__global__ __launch_bounds__(256)
void k_scores(const unsigned short* __restrict__ Gpart, const float* __restrict__ Spart,
              const float* __restrict__ wqg, const float* __restrict__ bqg,
              const float* __restrict__ wkg, const float* __restrict__ bkg,
              const float* __restrict__ wvg, const float* __restrict__ bvg,
              const float* __restrict__ wql, const float* __restrict__ bql,
              const float* __restrict__ wkl, const float* __restrict__ bkl,
              const float* __restrict__ wvl, const float* __restrict__ bvl,
              const float* __restrict__ wp,  const float* __restrict__ bp,
              unsigned short* __restrict__ Wf, float* __restrict__ beta, int nchunk)
{
    __shared__ float sSq[256], sSk[256];
    const int t  = threadIdx.x;
    const int bh = blockIdx.x >> 5;
    const int rg = blockIdx.x & 31;
    const int h  = bh & 3;

    float aq = 0.f, ak = 0.f;
    for (int c = 0; c < nchunk; ++c) {
        const float* sp = Spart + (size_t)(bh * nchunk + c) * 512;
        aq += sp[t]; ak += sp[256 + t];
    }
    sSq[t] = aq; sSk[t] = ak;
    __syncthreads();

    const int dl  = t >> 5;
    const int de  = rg * 8 + dl;
    const int e8  = (t & 31) * 8;
    const int cd  = h * DHEAD + de;
    const int ce0 = h * DHEAD + e8;

    float g[8] = {0.f, 0.f, 0.f, 0.f, 0.f, 0.f, 0.f, 0.f};
    const unsigned short* gpb = Gpart + (size_t)bh * nchunk * 65536 + (size_t)de * 256 + e8;
    for (int c = 0; c < nchunk; ++c) {
        h16x8 v = *reinterpret_cast<const h16x8*>(gpb + (size_t)c * 65536);
#pragma unroll
        for (int j = 0; j < 8; ++j) g[j] += (float)v[j];
    }

    const float sqv = sSq[de];
    float skv[8];
#pragma unroll
    for (int j = 0; j < 8; ++j) skv[j] = sSk[e8 + j];

    float wrow[8] = {0.f, 0.f, 0.f, 0.f, 0.f, 0.f, 0.f, 0.f};
    float bacc = 0.f;
    const float scale = 0.03125f;
#pragma unroll
    for (int br = 0; br < 2; ++br) {
        const float* wq = br ? wql : wqg;  const float* bq = br ? bql : bqg;
        const float* wk = br ? wkl : wkg;  const float* bk = br ? bkl : bkg;
        const float* wv = br ? wvl : wvg;  const float* bv = br ? bvl : bvg;
        const float wqv = wq[cd], bqv = bq[cd];

        float s[8], mm = -1e30f;
#pragma unroll
        for (int j = 0; j < 8; ++j) {
            const float wkv = wk[ce0 + j], bkv = bk[ce0 + j];
            s[j] = scale * (wqv * wkv * g[j] + wqv * bkv * sqv
                            + bqv * wkv * skv[j] + bqv * bkv * 16384.0f);
            mm = fmaxf(mm, s[j]);
        }
#pragma unroll
        for (int off = 16; off; off >>= 1) mm = fmaxf(mm, __shfl_xor(mm, off));
        float p[8], sum = 0.f;
#pragma unroll
        for (int j = 0; j < 8; ++j) { p[j] = __expf(s[j] - mm); sum += p[j]; }
#pragma unroll
        for (int off = 16; off; off >>= 1) sum += __shfl_xor(sum, off);
        const float inv = 1.f / sum;
#pragma unroll
        for (int j = 0; j < 8; ++j) {
            const float a = p[j] * inv;
            wrow[j] += a * wv[ce0 + j];
            bacc    += a * bv[ce0 + j];
        }
    }
    const float wp2 = 2.f * wp[cd];
    u16x8 pw;
#pragma unroll
    for (int j = 0; j < 8; ++j) pw[j] = f2bf(wp2 * wrow[j]);
    const int ks = e8 >> 5, ew = e8 & 31;
    *reinterpret_cast<u16x8*>(Wf + (size_t)bh * 65536 + ((ks * 256 + de) * 32 + ew)) = pw;
#pragma unroll
    for (int off = 16; off; off >>= 1) bacc += __shfl_xor(bacc, off);
    if ((t & 31) == 0) beta[bh * 256 + de] = wp2 * bacc + bp[cd];
}

// ---------------------------------------------------------------------------
// Kernel 3: Out[n][dd] = sum_e W[dd][e]*v[n][ce] + beta[dd].
// 128-row tiles, 8 waves, 16-row staging sub-phases, 2 blocks/CU. All 8 bh
// blocks of a tile share XCD tile%8 -> complementary full-row v reads.
// ---------------------------------------------------------------------------
__global__ __launch_bounds__(512, 4)
void k_out(const float* __restrict__ v, const unsigned short* __restrict__ Wf,
           const float* __restrict__ beta, float* __restrict__ out)
{
    __shared__ __align__(16) unsigned short lv[128 * 256];   // 64 KB
    const int t    = threadIdx.x;
    const int bh   = blockIdx.x >> 7;
    const int tile = blockIdx.x & 127;
    const int b    = bh >> 2, h = bh & 3;
    const int n0   = tile * 128;

    const int nr = t >> 5, ch0 = (t & 31) * 8;
    const float* vp = v + ((size_t)b * NTOK + n0 + nr) * CDIM + (size_t)h * DHEAD + ch0;

    f32x4 sA[2], sB[2];
#define VLOAD(dst, i) do { const size_t o_ = (size_t)(i) * 16 * CDIM;              \
        dst[0] = *reinterpret_cast<const f32x4*>(vp + o_);                         \
        dst[1] = *reinterpret_cast<const f32x4*>(vp + o_ + 4); } while (0)

    VLOAD(sA, 0);
    VLOAD(sB, 1);
#pragma unroll
    for (int i = 0; i < 8; i += 2) {
        {
            const int n = i * 16 + nr;
            u16x8 p;
#pragma unroll
            for (int j = 0; j < 4; ++j) { p[j] = f2bf(sA[0][j]); p[4 + j] = f2bf(sA[1][j]); }
            *reinterpret_cast<u16x8*>(&lv[n * 256 + (((t & 31) ^ (n & 7)) * 8)]) = p;
        }
        if (i + 2 < 8) VLOAD(sA, i + 2);
        {
            const int n = (i + 1) * 16 + nr;
            u16x8 p;
#pragma unroll
            for (int j = 0; j < 4; ++j) { p[j] = f2bf(sB[0][j]); p[4 + j] = f2bf(sB[1][j]); }
            *reinterpret_cast<u16x8*>(&lv[n * 256 + (((t & 31) ^ (n & 7)) * 8)]) = p;
        }
        if (i + 3 < 8) VLOAD(sB, i + 3);
    }
#undef VLOAD
    __syncthreads();

    const int w = t >> 6, lane = t & 63, li = lane & 15, g = lane >> 4;
    const int nw  = (w >> 1) * 32;
    const int dd0 = (w & 1) * 128;
    const unsigned short* wf = Wf + (size_t)bh * 65536;

    f32x4 acc[2][8];
#pragma unroll
    for (int r = 0; r < 2; ++r)
#pragma unroll
        for (int c = 0; c < 8; ++c) acc[r][c] = (f32x4){0.f, 0.f, 0.f, 0.f};

#pragma unroll
    for (int ks = 0; ks < 8; ++ks) {
        s16x8 af[2];
#pragma unroll
        for (int r = 0; r < 2; ++r) {
            const int n = nw + r * 16 + li;
            af[r] = *reinterpret_cast<const s16x8*>(&lv[n * 256 + (((ks * 4 + g) ^ (n & 7)) * 8)]);
        }
#pragma unroll
        for (int c = 0; c < 8; ++c) {
            const int dd = dd0 + c * 16 + li;
            const s16x8 bf = *reinterpret_cast<const s16x8*>(wf + ((ks * 256 + dd) * 32 + g * 8));
            acc[0][c] = __builtin_amdgcn_mfma_f32_16x16x32_bf16(af[0], bf, acc[0][c], 0, 0, 0);
            acc[1][c] = __builtin_amdgcn_mfma_f32_16x16x32_bf16(af[1], bf, acc[1][c], 0, 0, 0);
        }
    }

    float betar[8];
#pragma unroll
    for (int c = 0; c < 8; ++c) betar[c] = beta[bh * 256 + dd0 + c * 16 + li];

#pragma unroll
    for (int r = 0; r < 2; ++r)
#pragma unroll
        for (int c = 0; c < 8; ++c) {
            const int dd = dd0 + c * 16 + li;
#pragma unroll
            for (int reg = 0; reg < 4; ++reg) {
                const int n = nw + r * 16 + g * 4 + reg;
                out[((size_t)b * NTOK + n0 + n) * CDIM + (size_t)h * DHEAD + dd] =
                    acc[r][c][reg] + betar[c];
            }
        }
}

// ---------------------------------------------------------------------------
extern "C" void kernel_launch(void* const* d_in, const int* in_sizes, int n_in,
                              void* d_out, int out_size, void* d_ws, size_t ws_size,
                              hipStream_t stream)
{
    const float* q = (const float*)d_in[0];
    const float* k = (const float*)d_in[1];
    const float* v = (const float*)d_in[2];
    const float* wgt[14];
    for (int i = 0; i < 14; ++i) wgt[i] = (const float*)d_in[3 + i];
    float* out = (float*)d_out;

    int nchunk = 32;
    while (nchunk > 1) {
        size_t need = (size_t)8 * nchunk * 65536 * 2   // Gpart fp16
                    + (size_t)8 * nchunk * 512 * 4     // Spart
                    + (size_t)8 * 65536 * 2            // Wf bf16
                    + (size_t)8 * 256 * 4 + 1024;      // beta + slack
        if (need <= ws_size) break;
        nchunk >>= 1;
    }

    char* p = (char*)d_ws;
    unsigned short* Gpart = (unsigned short*)p; p += (size_t)8 * nchunk * 65536 * 2;
    float* Spart = (float*)p;                   p += (size_t)8 * nchunk * 512 * 4;
    unsigned short* Wf = (unsigned short*)p;    p += (size_t)8 * 65536 * 2;
    float* beta  = (float*)p;

    k_gram<<<dim3(8 * nchunk * 2), dim3(512), 0, stream>>>(q, k, Gpart, Spart, nchunk);
    k_scores<<<dim3(8 * 32), dim3(256), 0, stream>>>(
        Gpart, Spart,
        wgt[0], wgt[1], wgt[2], wgt[3], wgt[4], wgt[5],
        wgt[6], wgt[7], wgt[8], wgt[9], wgt[10], wgt[11],
        wgt[12], wgt[13], Wf, beta, nchunk);
    k_out<<<dim3(8 * 128), dim3(512), 0, stream>>>(v, Wf, beta, out);
}

// Round 11
// 209.558 us; speedup vs baseline: 1.0745x; 1.0745x over previous
//
#include <hip/hip_runtime.h>
#include <stdint.h>

#define NTOK 16384
#define CDIM 1024
#define DHEAD 256

typedef short s16x8 __attribute__((ext_vector_type(8)));
typedef unsigned short u16x8 __attribute__((ext_vector_type(8)));
typedef _Float16 h16x8 __attribute__((ext_vector_type(8)));
typedef float f32x4 __attribute__((ext_vector_type(4)));
typedef float f32x16 __attribute__((ext_vector_type(16)));

static __device__ __forceinline__ unsigned short f2bf(float f) {
    union { float f; unsigned u; } x; x.f = f;
    unsigned r = (x.u + 0x7fffu + ((x.u >> 16) & 1u)) >> 16;
    return (unsigned short)r;
}
static __device__ __forceinline__ unsigned short f2h(float f) {
    _Float16 h = (_Float16)f;
    return __builtin_bit_cast(unsigned short, h);
}
static __device__ __forceinline__ unsigned cvtpk(float lo, float hi) {
    unsigned r;
    asm("v_cvt_pk_bf16_f32 %0, %1, %2" : "=v"(r) : "v"(lo), "v"(hi));
    return r;
}
// Barrier ordering LDS only — global loads stay in flight across it (T4).
static __device__ __forceinline__ void lgkm_barrier() {
    asm volatile("s_waitcnt lgkmcnt(0)" ::: "memory");
    __builtin_amdgcn_s_barrier();
}

// ---------------------------------------------------------------------------
// Kernel 1: partial Gram G[de][e] over an n-chunk + per-channel sums.
// OCCUPANCY-FIRST redesign: tile 256(de) x 64(e), es-split x4. Wave-tile
// 64x32 -> acc only 32 AGPR; staging 32; ~110 unified regs < 128 cap at
// launch_bounds(512,4) -> 4 waves/SIMD = 2 RESIDENT BLOCKS/CU (every >=2
// blk/CU variant beat every 1 blk/CU variant across R1-R10). LDS 10 KB.
// Co-XCD: P = t8 + 8*es + 32*thi -> all 8bh x 4es of chunk c on XCD c%8,
// full 4KB rows consumed collectively, L2 dedups (R10: FETCH 131 MB).
// Depth-2 register staging, lgkm-only barriers, 16-row stages.
// ---------------------------------------------------------------------------
__global__ __launch_bounds__(512, 4)
void k_gram(const float* __restrict__ q, const float* __restrict__ k,
            unsigned short* __restrict__ Gpart, float* __restrict__ Spart, int nchunk)
{
    __shared__ __align__(16) ushort4 lq4[4 * 256];   // 8 KB: [rowgrp][ch^rowgrp]
    __shared__ __align__(16) ushort4 lk4[4 * 64];    // 2 KB

    const int P   = blockIdx.x;
    const int t8  = P & 7;
    const int es  = (P >> 3) & 3;
    const int thi = P >> 5;
    const int T   = thi * 8 + t8;
    const int bh  = T / nchunk;
    const int chunk = T - bh * nchunk;
    const int b = bh >> 2, h = bh & 3;
    const int rows = NTOK / nchunk;
    const int S    = rows >> 4;              // 16-row stages
    const int n0c  = chunk * rows;

    const int t = threadIdx.x;
    const int lane = t & 63, w = t >> 6;
    const int l31 = lane & 31, g2 = lane >> 5;
    const int wr = w >> 1, wc = w & 1;       // de-group*64, e-half*32

    // staging roles: t<256 -> q (64 ch-quads x 4 row-grps); t in [256,320) -> k
    const bool qt = t < 256;
    const bool kt = (t >= 256) && (t < 320);
    const int qcq = t >> 2, qrg = t & 3;
    const int kid = t - 256;
    const int kcq = kid >> 2, krg = kid & 3;

    const float* qp = q + ((size_t)(b * NTOK + n0c + qrg * 4)) * CDIM + h * DHEAD + qcq * 4;
    const float* kp = k + ((size_t)(b * NTOK + n0c + krg * 4)) * CDIM + h * DHEAD + es * 64 + kcq * 4;

    f32x4 sgA[4], sgB[4];
#define LOADSET(dst, s) do {                                                   \
        if (qt) { _Pragma("unroll") for (int j_ = 0; j_ < 4; ++j_)              \
            dst[j_] = *reinterpret_cast<const f32x4*>(qp + ((size_t)(s) * 16 + j_) * CDIM); } \
        else if (kt) { _Pragma("unroll") for (int j_ = 0; j_ < 4; ++j_)         \
            dst[j_] = *reinterpret_cast<const f32x4*>(kp + ((size_t)(s) * 16 + j_) * CDIM); } \
    } while (0)

    float ssum[4] = {0.f, 0.f, 0.f, 0.f};
#define CONSUME(src) do {                                                      \
        if (qt) {                                                               \
            _Pragma("unroll") for (int c_ = 0; c_ < 4; ++c_) {                  \
                const int ch_ = qcq * 4 + c_;                                   \
                ushort4 p_;                                                     \
                p_.x = f2bf(src[0][c_]); p_.y = f2bf(src[1][c_]);               \
                p_.z = f2bf(src[2][c_]); p_.w = f2bf(src[3][c_]);               \
                ssum[c_] += (src[0][c_] + src[1][c_]) + (src[2][c_] + src[3][c_]); \
                lq4[qrg * 256 + (ch_ ^ qrg)] = p_;                              \
            }                                                                   \
        } else if (kt) {                                                        \
            _Pragma("unroll") for (int c_ = 0; c_ < 4; ++c_) {                  \
                const int ch_ = kcq * 4 + c_;                                   \
                ushort4 p_;                                                     \
                p_.x = f2bf(src[0][c_]); p_.y = f2bf(src[1][c_]);               \
                p_.z = f2bf(src[2][c_]); p_.w = f2bf(src[3][c_]);               \
                ssum[c_] += (src[0][c_] + src[1][c_]) + (src[2][c_] + src[3][c_]); \
                lk4[krg * 64 + (ch_ ^ krg)] = p_;                               \
            }                                                                   \
        }                                                                       \
    } while (0)

    f32x16 acc[2];
#pragma unroll
    for (int r = 0; r < 2; ++r)
#pragma unroll
        for (int j = 0; j < 16; ++j) acc[r][j] = 0.f;

    const uint2* lqu = reinterpret_cast<const uint2*>(lq4);
    const uint2* lku = reinterpret_cast<const uint2*>(lk4);
    const int gLo = 2 * g2, gHi = 2 * g2 + 1;

#define MFMAPHASE() do {                                                       \
        s16x8 af_[2], bf_;                                                     \
        _Pragma("unroll") for (int r_ = 0; r_ < 2; ++r_) {                     \
            const int ch_ = wr * 64 + r_ * 32 + l31;                           \
            const uint2 lo_ = lqu[gLo * 256 + (ch_ ^ gLo)];                    \
            const uint2 hi_ = lqu[gHi * 256 + (ch_ ^ gHi)];                    \
            int4 f_; f_.x = lo_.x; f_.y = lo_.y; f_.z = hi_.x; f_.w = hi_.y;   \
            af_[r_] = __builtin_bit_cast(s16x8, f_);                           \
        }                                                                       \
        {                                                                       \
            const int ch_ = wc * 32 + l31;                                     \
            const uint2 lo_ = lku[gLo * 64 + (ch_ ^ gLo)];                     \
            const uint2 hi_ = lku[gHi * 64 + (ch_ ^ gHi)];                     \
            int4 f_; f_.x = lo_.x; f_.y = lo_.y; f_.z = hi_.x; f_.w = hi_.y;   \
            bf_ = __builtin_bit_cast(s16x8, f_);                               \
        }                                                                       \
        acc[0] = __builtin_amdgcn_mfma_f32_32x32x16_bf16(af_[0], bf_, acc[0], 0, 0, 0); \
        acc[1] = __builtin_amdgcn_mfma_f32_32x32x16_bf16(af_[1], bf_, acc[1], 0, 0, 0); \
    } while (0)

    LOADSET(sgA, 0);
    LOADSET(sgB, 1);

    for (int s = 0; s < S; s += 2) {
        CONSUME(sgA);
        if (s + 2 < S) LOADSET(sgA, s + 2);
        lgkm_barrier();
        MFMAPHASE();
        lgkm_barrier();

        CONSUME(sgB);
        if (s + 3 < S) LOADSET(sgB, s + 3);
        lgkm_barrier();
        MFMAPHASE();
        lgkm_barrier();
    }
#undef LOADSET
#undef CONSUME
#undef MFMAPHASE

    // ---- channel sums ----
#pragma unroll
    for (int off = 1; off < 4; off <<= 1)
#pragma unroll
        for (int c = 0; c < 4; ++c) ssum[c] += __shfl_xor(ssum[c], off);
    float* sp = Spart + (size_t)(bh * nchunk + chunk) * 512;
    if (qt && (t & 3) == 0 && es == 0)
        *reinterpret_cast<float4*>(&sp[qcq * 4]) = make_float4(ssum[0], ssum[1], ssum[2], ssum[3]);
    if (kt && (kid & 3) == 0)
        *reinterpret_cast<float4*>(&sp[256 + es * 64 + kcq * 4]) =
            make_float4(ssum[0], ssum[1], ssum[2], ssum[3]);

    // ---- Gpart fp16 direct store (64-e slice = one 128B line per de row) ----
    unsigned short* gp = Gpart + (size_t)(bh * nchunk + chunk) * 65536;
#pragma unroll
    for (int r = 0; r < 2; ++r)
#pragma unroll
        for (int reg = 0; reg < 16; ++reg) {
            const int de = wr * 64 + r * 32 + (reg & 3) + 8 * (reg >> 2) + 4 * g2;
            const int e  = es * 64 + wc * 32 + l31;
            gp[(size_t)de * 256 + e] = f2h(acc[r][reg]);
        }
}

// ---------------------------------------------------------------------------
// Kernel 2: fused chunk-reduce + scores + softmax (both branches) + W/beta.
// Wf row-major [dd][e] bf16 (R8 pair).
// ---------------------------------------------------------------------------
__global__ __launch_bounds__(256)
void k_scores(const unsigned short* __restrict__ Gpart, const float* __restrict__ Spart,
              const float* __restrict__ wqg, const float* __restrict__ bqg,
              const float* __restrict__ wkg, const float* __restrict__ bkg,
              const float* __restrict__ wvg, const float* __restrict__ bvg,
              const float* __restrict__ wql, const float* __restrict__ bql,
              const float* __restrict__ wkl, const float* __restrict__ bkl,
              const float* __restrict__ wvl, const float* __restrict__ bvl,
              const float* __restrict__ wp,  const float* __restrict__ bp,
              unsigned short* __restrict__ Wf, float* __restrict__ beta, int nchunk)
{
    __shared__ float sSq[256], sSk[256];
    const int t  = threadIdx.x;
    const int bh = blockIdx.x >> 5;
    const int rg = blockIdx.x & 31;
    const int h  = bh & 3;

    float aq = 0.f, ak = 0.f;
    for (int c = 0; c < nchunk; ++c) {
        const float* sp = Spart + (size_t)(bh * nchunk + c) * 512;
        aq += sp[t]; ak += sp[256 + t];
    }
    sSq[t] = aq; sSk[t] = ak;
    __syncthreads();

    const int dl  = t >> 5;
    const int de  = rg * 8 + dl;
    const int e8  = (t & 31) * 8;
    const int cd  = h * DHEAD + de;
    const int ce0 = h * DHEAD + e8;

    float g[8] = {0.f, 0.f, 0.f, 0.f, 0.f, 0.f, 0.f, 0.f};
    const unsigned short* gpb = Gpart + (size_t)bh * nchunk * 65536 + (size_t)de * 256 + e8;
    for (int c = 0; c < nchunk; ++c) {
        h16x8 v = *reinterpret_cast<const h16x8*>(gpb + (size_t)c * 65536);
#pragma unroll
        for (int j = 0; j < 8; ++j) g[j] += (float)v[j];
    }

    const float sqv = sSq[de];
    float skv[8];
#pragma unroll
    for (int j = 0; j < 8; ++j) skv[j] = sSk[e8 + j];

    float wrow[8] = {0.f, 0.f, 0.f, 0.f, 0.f, 0.f, 0.f, 0.f};
    float bacc = 0.f;
    const float scale = 0.03125f;
#pragma unroll
    for (int br = 0; br < 2; ++br) {
        const float* wq = br ? wql : wqg;  const float* bq = br ? bql : bqg;
        const float* wk = br ? wkl : wkg;  const float* bk = br ? bkl : bkg;
        const float* wv = br ? wvl : wvg;  const float* bv = br ? bvl : bvg;
        const float wqv = wq[cd], bqv = bq[cd];

        float s[8], mm = -1e30f;
#pragma unroll
        for (int j = 0; j < 8; ++j) {
            const float wkv = wk[ce0 + j], bkv = bk[ce0 + j];
            s[j] = scale * (wqv * wkv * g[j] + wqv * bkv * sqv
                            + bqv * wkv * skv[j] + bqv * bkv * 16384.0f);
            mm = fmaxf(mm, s[j]);
        }
#pragma unroll
        for (int off = 16; off; off >>= 1) mm = fmaxf(mm, __shfl_xor(mm, off));
        float p[8], sum = 0.f;
#pragma unroll
        for (int j = 0; j < 8; ++j) { p[j] = __expf(s[j] - mm); sum += p[j]; }
#pragma unroll
        for (int off = 16; off; off >>= 1) sum += __shfl_xor(sum, off);
        const float inv = 1.f / sum;
#pragma unroll
        for (int j = 0; j < 8; ++j) {
            const float a = p[j] * inv;
            wrow[j] += a * wv[ce0 + j];
            bacc    += a * bv[ce0 + j];
        }
    }
    const float wp2 = 2.f * wp[cd];
    u16x8 pw;
#pragma unroll
    for (int j = 0; j < 8; ++j) pw[j] = f2bf(wp2 * wrow[j]);
    *reinterpret_cast<u16x8*>(Wf + (size_t)bh * 65536 + (size_t)de * 256 + e8) = pw;
#pragma unroll
    for (int off = 16; off; off >>= 1) bacc += __shfl_xor(bacc, off);
    if ((t & 31) == 0) beta[bh * 256 + de] = wp2 * bacc + bp[cd];
}

// ---------------------------------------------------------------------------
// Kernel 3: Out[n][dd] = sum_e W[dd][e]*v[n][ce] + beta[dd].  (R8 verbatim —
// best measured config: no LDS/barriers, direct v reads, Wf L2-hot.)
// ---------------------------------------------------------------------------
__global__ __launch_bounds__(256, 2)
void k_out(const float* __restrict__ v, const unsigned short* __restrict__ Wf,
           const float* __restrict__ beta, float* __restrict__ out)
{
    const int P    = blockIdx.x;
    const int bh   = P & 7;
    const int tile = P >> 3;
    const int b    = bh >> 2, h = bh & 3;

    const int t = threadIdx.x;
    const int w = t >> 6, lane = t & 63;
    const int l31 = lane & 31, g2 = lane >> 5;
    const int n0 = tile * 128 + w * 32;

    const float* pv = v + (size_t)(b * NTOK + n0 + l31) * CDIM + h * DHEAD + g2 * 8;
    const unsigned short* pw = Wf + (size_t)bh * 65536 + (size_t)l31 * 256 + g2 * 8;

    f32x4 Aa[2], Ab[2];
    u16x8 Ba[8], Bb[8];

#define LDSTEP(av, bv2, ks) do {                                              \
        av[0] = *reinterpret_cast<const f32x4*>(pv + (ks) * 16);               \
        av[1] = *reinterpret_cast<const f32x4*>(pv + (ks) * 16 + 4);           \
        _Pragma("unroll") for (int dg = 0; dg < 8; ++dg)                       \
            bv2[dg] = *reinterpret_cast<const u16x8*>(pw + (size_t)dg * 8192 + (ks) * 16); \
    } while (0)

    f32x16 acc[8];
#pragma unroll
    for (int dg = 0; dg < 8; ++dg)
#pragma unroll
        for (int j = 0; j < 16; ++j) acc[dg][j] = 0.f;

#define CPSTEP(av, bv2) do {                                                  \
        int4 A;                                                               \
        A.x = cvtpk(av[0][0], av[0][1]); A.y = cvtpk(av[0][2], av[0][3]);     \
        A.z = cvtpk(av[1][0], av[1][1]); A.w = cvtpk(av[1][2], av[1][3]);     \
        const s16x8 fA = __builtin_bit_cast(s16x8, A);                        \
        _Pragma("unroll") for (int dg = 0; dg < 8; ++dg)                      \
            acc[dg] = __builtin_amdgcn_mfma_f32_32x32x16_bf16(                \
                fA, __builtin_bit_cast(s16x8, bv2[dg]), acc[dg], 0, 0, 0);    \
    } while (0)

    LDSTEP(Aa, Ba, 0);
#pragma unroll
    for (int ks = 0; ks < 16; ks += 2) {
        if (ks + 1 < 16) LDSTEP(Ab, Bb, ks + 1);
        CPSTEP(Aa, Ba);
        if (ks + 2 < 16) LDSTEP(Aa, Ba, ks + 2);
        if (ks + 1 < 16) CPSTEP(Ab, Bb);
    }
#undef LDSTEP
#undef CPSTEP

#pragma unroll
    for (int dg = 0; dg < 8; ++dg) {
        const float bb = beta[bh * 256 + dg * 32 + l31];
#pragma unroll
        for (int reg = 0; reg < 16; ++reg) {
            const int row = (reg & 3) + 8 * (reg >> 2) + 4 * g2;
            out[(size_t)(b * NTOK + n0 + row) * CDIM + h * DHEAD + dg * 32 + l31] =
                acc[dg][reg] + bb;
        }
    }
}

// ---------------------------------------------------------------------------
extern "C" void kernel_launch(void* const* d_in, const int* in_sizes, int n_in,
                              void* d_out, int out_size, void* d_ws, size_t ws_size,
                              hipStream_t stream)
{
    const float* q = (const float*)d_in[0];
    const float* k = (const float*)d_in[1];
    const float* v = (const float*)d_in[2];
    const float* wgt[14];
    for (int i = 0; i < 14; ++i) wgt[i] = (const float*)d_in[3 + i];
    float* out = (float*)d_out;

    int nchunk = 32;
    while (nchunk > 1) {
        size_t need = (size_t)8 * nchunk * 65536 * 2   // Gpart fp16
                    + (size_t)8 * nchunk * 512 * 4     // Spart
                    + (size_t)8 * 65536 * 2            // Wf bf16
                    + (size_t)8 * 256 * 4 + 1024;      // beta + slack
        if (need <= ws_size) break;
        nchunk >>= 1;
    }

    char* p = (char*)d_ws;
    unsigned short* Gpart = (unsigned short*)p; p += (size_t)8 * nchunk * 65536 * 2;
    float* Spart = (float*)p;                   p += (size_t)8 * nchunk * 512 * 4;
    unsigned short* Wf = (unsigned short*)p;    p += (size_t)8 * 65536 * 2;
    float* beta  = (float*)p;

    k_gram<<<dim3(32 * nchunk), dim3(512), 0, stream>>>(q, k, Gpart, Spart, nchunk);
    k_scores<<<dim3(8 * 32), dim3(256), 0, stream>>>(
        Gpart, Spart,
        wgt[0], wgt[1], wgt[2], wgt[3], wgt[4], wgt[5],
        wgt[6], wgt[7], wgt[8], wgt[9], wgt[10], wgt[11],
        wgt[12], wgt[13], Wf, beta, nchunk);
    k_out<<<dim3(8 * 128), dim3(256), 0, stream>>>(v, Wf, beta, out);
}